// Round 8
// baseline (245.626 us; speedup 1.0000x reference)
//
#include <hip/hip_runtime.h>
#include <hip/hip_bf16.h>

#define NB 2
#define NS 2048
#define NH 16
#define ND 64
#define NHID 1024

// exp(x/32) = exp2(x * log2(e)/32) ; folded into Wq/bq at conversion time
#define QSCALE 0.045084220f

typedef __attribute__((ext_vector_type(8))) short bf16x8;
typedef __attribute__((ext_vector_type(4))) short s16x4;
typedef __attribute__((ext_vector_type(4))) float f32x4;

typedef __attribute__((address_space(3))) unsigned int lds_u32;
typedef __attribute__((address_space(1))) unsigned int glb_u32;

__device__ inline void gl_lds16(const void* g, void* l) {
  __builtin_amdgcn_global_load_lds((const glb_u32*)g, (lds_u32*)l, 16, 0, 0);
}

__device__ inline short f2bf(float f) {
  __hip_bfloat16 h = __float2bfloat16(f);
  short s; __builtin_memcpy(&s, &h, 2); return s;
}

__device__ inline bf16x8 cvt8(const float* __restrict__ p) {
  float4 x = *(const float4*)p;
  float4 y = *(const float4*)(p + 4);
  bf16x8 r;
  r[0] = f2bf(x.x); r[1] = f2bf(x.y); r[2] = f2bf(x.z); r[3] = f2bf(x.w);
  r[4] = f2bf(y.x); r[5] = f2bf(y.y); r[6] = f2bf(y.z); r[7] = f2bf(y.w);
  return r;
}

// ---------------------------------------------------------------------------
// Kernel 0: prep = pack_mask (blocks 0..1023) + weight cvt (blocks 1024..2059)
// ---------------------------------------------------------------------------
__global__ __launch_bounds__(256) void prep(
    const int* __restrict__ mask, unsigned* __restrict__ mp,
    const float* __restrict__ Wq, const float* __restrict__ Wk,
    const float* __restrict__ Wv, const float* __restrict__ Wo,
    short* __restrict__ Wq_b, short* __restrict__ Wk_b,
    short* __restrict__ Wv_b, short* __restrict__ Wo_b)
{
  if (blockIdx.x < 1024) {
    int idx = blockIdx.x * 256 + threadIdx.x;          // 0..262143
    const int4* src = (const int4*)(mask + (long)idx * 32);
    unsigned w = 0;
#pragma unroll
    for (int i = 0; i < 8; ++i) {
      int4 v = src[i];
      w |= (v.x != 0 ? 1u : 0u) << (i * 4 + 0);
      w |= (v.y != 0 ? 1u : 0u) << (i * 4 + 1);
      w |= (v.z != 0 ? 1u : 0u) << (i * 4 + 2);
      w |= (v.w != 0 ? 1u : 0u) << (i * 4 + 3);
    }
    mp[idx] = w;
  } else {
    int i = ((blockIdx.x - 1024) * 256 + threadIdx.x) * 4;  // 0..1060860
    const float* src; short* dst; int off; float sc = 1.0f;
    if (i < 1048576)      { src = Wo; dst = Wo_b; off = i; }
    else {
      int j = i - 1048576;
      if (j < 4096)       { src = Wq; dst = Wq_b; off = j; sc = QSCALE; }
      else if (j < 8192)  { src = Wk; dst = Wk_b; off = j - 4096; }
      else                { src = Wv; dst = Wv_b; off = j - 8192; }
    }
    float4 v = *(const float4*)(src + off);
    s16x4 o;
    o[0] = f2bf(v.x * sc); o[1] = f2bf(v.y * sc);
    o[2] = f2bf(v.z * sc); o[3] = f2bf(v.w * sc);
    *(s16x4*)(dst + off) = o;
  }
}

// ---------------------------------------------------------------------------
// Kernel 1: Q,K projection. Block = 4 waves, wave = 1 token (16 heads).
// ---------------------------------------------------------------------------
__global__ __launch_bounds__(256) void qk_proj(
    const float* __restrict__ qin, const float* __restrict__ kin,
    const short* __restrict__ Wq_b, const float* __restrict__ bq,
    const short* __restrict__ Wk_b, const float* __restrict__ bk,
    short* __restrict__ Qws, short* __restrict__ Kws)
{
  __shared__ __align__(16) short ldsT[4][16][72];
  const int tid = threadIdx.x;
  const int w = tid >> 6, lane = tid & 63;
  const int c = lane & 15, qq = lane >> 4;
  const int t = blockIdx.x * 4 + w;         // b*S + s
  const int b = t >> 11, s = t & (NS - 1);
  const int aoff = (t * 16 + c) * 64 + qq * 8;
  const int row0 = lane >> 3, inner = lane & 7;

#pragma unroll
  for (int m = 0; m < 2; ++m) {
    const float* X  = (m == 0) ? qin  : kin;
    const short* W  = (m == 0) ? Wq_b : Wk_b;
    const float* bb = (m == 0) ? bq   : bk;
    short* dst      = (m == 0) ? Qws  : Kws;
    const float bsc = (m == 0) ? QSCALE : 1.0f;

    bf16x8 a0 = cvt8(X + aoff);
    bf16x8 a1 = cvt8(X + aoff + 32);

#pragma unroll
    for (int nt = 0; nt < 4; ++nt) {
      f32x4 z = {0.f, 0.f, 0.f, 0.f};
      const short* wp = W + (nt * 16 + c) * 64 + qq * 8;
      bf16x8 b0 = *(const bf16x8*)(wp);
      bf16x8 b1 = *(const bf16x8*)(wp + 32);
      z = __builtin_amdgcn_mfma_f32_16x16x32_bf16(a0, b0, z, 0, 0, 0);
      z = __builtin_amdgcn_mfma_f32_16x16x32_bf16(a1, b1, z, 0, 0, 0);
      float bias = bb[nt * 16 + c] * bsc;
#pragma unroll
      for (int r = 0; r < 4; ++r)           // C row = head = qq*4+r
        ldsT[w][qq * 4 + r][nt * 16 + c] = f2bf(z[r] + bias);
    }

    bf16x8 v0 = *(const bf16x8*)&ldsT[w][row0][inner * 8];
    bf16x8 v1 = *(const bf16x8*)&ldsT[w][row0 + 8][inner * 8];
    int bh0 = b * NH + row0, bh1 = b * NH + row0 + 8;
    *(bf16x8*)(dst + (bh0 * NS + s) * 64 + inner * 8) = v0;
    *(bf16x8*)(dst + (bh1 * NS + s) * 64 + inner * 8) = v1;
  }
}

// ---------------------------------------------------------------------------
// Kernel 1b: V projection + 64x64 transpose. Block = 4 waves, wave = 16 tokens.
// ---------------------------------------------------------------------------
__global__ __launch_bounds__(256) void vproj(
    const float* __restrict__ vin, const short* __restrict__ Wv_b,
    const float* __restrict__ bv, short* __restrict__ Vt)
{
  __shared__ __align__(16) short ldsVT[64][72];   // [d][token]
  const int tid = threadIdx.x;
  const int g = tid >> 6, lane = tid & 63;
  const int c = lane & 15, qq = lane >> 4;
  const int bh = blockIdx.x >> 5;
  const int stile = blockIdx.x & 31;
  const int b = bh >> 4, h = bh & 15;
  const int sb = stile * 64;

  bf16x8 wv[8];
  float bias[4];
#pragma unroll
  for (int nt = 0; nt < 4; ++nt) {
    const short* wp = Wv_b + (nt * 16 + c) * 64 + qq * 8;
    wv[nt * 2]     = *(const bf16x8*)(wp);
    wv[nt * 2 + 1] = *(const bf16x8*)(wp + 32);
    bias[nt] = bv[nt * 16 + c];
  }

  const float* ap = vin + ((size_t)((b * NS + sb + 16 * g + c) * 16 + h)) * 64 + qq * 8;
  bf16x8 a0 = cvt8(ap);
  bf16x8 a1 = cvt8(ap + 32);
#pragma unroll
  for (int nt = 0; nt < 4; ++nt) {
    f32x4 z = {0.f, 0.f, 0.f, 0.f};
    z = __builtin_amdgcn_mfma_f32_16x16x32_bf16(a0, wv[nt * 2], z, 0, 0, 0);
    z = __builtin_amdgcn_mfma_f32_16x16x32_bf16(a1, wv[nt * 2 + 1], z, 0, 0, 0);
    ushort4 u;
    u.x = (unsigned short)f2bf(z[0] + bias[nt]);
    u.y = (unsigned short)f2bf(z[1] + bias[nt]);
    u.z = (unsigned short)f2bf(z[2] + bias[nt]);
    u.w = (unsigned short)f2bf(z[3] + bias[nt]);
    *(ushort4*)&ldsVT[nt * 16 + c][16 * g + qq * 4] = u;   // token = 16g+qq*4+r
  }
  __syncthreads();

#pragma unroll
  for (int j = 0; j < 2; ++j) {
    int idx = tid + 256 * j;            // 0..511
    int d = idx >> 3, unit = idx & 7;
    bf16x8 o = *(const bf16x8*)&ldsVT[d][unit * 8];
    *(bf16x8*)(Vt + ((size_t)(bh * 64 + d)) * NS + sb + unit * 8) = o;
  }
}

// ---------------------------------------------------------------------------
// Kernel 3: flash attention, transposed-score, wave = 64 q-rows (nq=4).
// Block = 2 waves = 128-row q-tile. Each K/V b128 LDS read now feeds 4 MFMAs
// (was 2) -> LDS-pipe pressure per element down 33%. Row sums via ones-MFMA
// (Osum = 1^T . P) -> no per-iter VALU adds, no epilogue shuffles.
// ---------------------------------------------------------------------------
__global__ __launch_bounds__(128) void attn(
    const short* __restrict__ Qws, const short* __restrict__ Kws,
    const short* __restrict__ Vt, const unsigned* __restrict__ Mp,
    short* __restrict__ AO)
{
  __shared__ __align__(16) short Ks[2][64][64];   // staged K tile (swizzled)
  __shared__ __align__(16) short Vs[2][64][64];   // staged V tile (swizzled)
  __shared__ __align__(16) short Ps[2][64][72];   // per-wave P^T tile [q][key]

  const int tid = threadIdx.x;
  const int w = tid >> 6, lane = tid & 63;
  const int c = lane & 15, qq = lane >> 4;
  const int bh = blockIdx.x & 31;                 // XCD swizzle
  const int qtile = blockIdx.x >> 5;              // 0..15
  const int b = bh >> 4, h = bh & 15;
  const int qbase = qtile * 128 + w * 64;         // this wave's 64 q-rows

  const short* Qp = Qws + (size_t)bh * (NS * 64);
  const short* Kp = Kws + (size_t)bh * (NS * 64);
  const short* Vp = Vt + (size_t)bh * (64 * NS);
  const unsigned* mrow = Mp + (size_t)b * (NS * (NS / 32));

  // Q B-frags: 4 q-tiles x 2 k-halves (pre-scaled by QSCALE in qk_proj)
  bf16x8 aq[4][2];
#pragma unroll
  for (int nq = 0; nq < 4; ++nq) {
    const short* qp = Qp + (qbase + nq * 16 + c) * 64 + qq * 8;
    aq[nq][0] = *(const bf16x8*)(qp);
    aq[nq][1] = *(const bf16x8*)(qp + 32);
  }

  // ones A-frag for row-sum MFMA
  bf16x8 ones;
#pragma unroll
  for (int i = 0; i < 8; ++i) ones[i] = (short)0x3F80;

  const f32x4 ZV = {0.f, 0.f, 0.f, 0.f};
  f32x4 O[4][4];                                  // O^T: [nq][dt], reg = d
  f32x4 Osum[4];                                  // row sums (all regs equal)
#pragma unroll
  for (int nq = 0; nq < 4; ++nq) {
    Osum[nq] = ZV;
#pragma unroll
    for (int dt = 0; dt < 4; ++dt) O[nq][dt] = ZV;
  }

  const int srow = lane >> 3;
  const int sunit = (lane & 7) ^ srow;            // XOR swizzle (global side)
  auto stage = [&](int kt, int buf) {
#pragma unroll
    for (int i = 0; i < 4; ++i) {
      int j = w * 4 + i;                          // 8 chunks over 2 waves
      const short* gk = Kp + ((size_t)(kt * 64 + j * 8 + srow)) * 64 + sunit * 8;
      gl_lds16(gk, &Ks[buf][0][0] + j * 512);
      const short* gv = Vp + ((size_t)(j * 8 + srow)) * NS + kt * 64 + sunit * 8;
      gl_lds16(gv, &Vs[buf][0][0] + j * 512);
    }
  };

  stage(0, 0);
  __syncthreads();

  for (int kt = 0; kt < NS / 64; ++kt) {
    const int buf = kt & 1;
    if (kt < NS / 64 - 1) stage(kt + 1, buf ^ 1);

    // mask: one 64-bit word per q-row (lane c owns its q)
    uint2 mw[4];
#pragma unroll
    for (int nq = 0; nq < 4; ++nq)
      mw[nq] = *(const uint2*)(mrow +
          (size_t)(qbase + nq * 16 + c) * (NS / 32) + kt * 2);

    // S^T = K.Q^T per 16-key group; exp+mask+pack immediately (short st live)
#pragma unroll
    for (int mt = 0; mt < 4; ++mt) {
      const short* kb = &Ks[buf][mt * 16 + c][0];
      bf16x8 ak0 = *(const bf16x8*)(kb + ((qq ^ (c & 7)) << 3));
      bf16x8 ak1 = *(const bf16x8*)(kb + (((4 + qq) ^ (c & 7)) << 3));
#pragma unroll
      for (int nq = 0; nq < 4; ++nq) {
        f32x4 z = __builtin_amdgcn_mfma_f32_16x16x32_bf16(ak0, aq[nq][0], ZV, 0, 0, 0);
        z = __builtin_amdgcn_mfma_f32_16x16x32_bf16(ak1, aq[nq][1], z, 0, 0, 0);
        unsigned wsel = (mt & 2) ? mw[nq].y : mw[nq].x;
        unsigned nib = (wsel >> (((mt & 1) << 4) + (qq << 2))) & 0xFu;
        float e0 = (nib & 1u) ? __builtin_amdgcn_exp2f(z[0]) : 0.f;
        float e1 = (nib & 2u) ? __builtin_amdgcn_exp2f(z[1]) : 0.f;
        float e2 = (nib & 4u) ? __builtin_amdgcn_exp2f(z[2]) : 0.f;
        float e3 = (nib & 8u) ? __builtin_amdgcn_exp2f(z[3]) : 0.f;
        ushort4 u;
        u.x = (unsigned short)f2bf(e0);
        u.y = (unsigned short)f2bf(e1);
        u.z = (unsigned short)f2bf(e2);
        u.w = (unsigned short)f2bf(e3);
        *(ushort4*)&Ps[w][nq * 16 + c][mt * 16 + (qq << 2)] = u;
      }
    }

    // O^T += V^T . P ; row sums via ones-MFMA on the same B-frags
#pragma unroll
    for (int ks = 0; ks < 2; ++ks) {
      bf16x8 pf[4];
#pragma unroll
      for (int nq = 0; nq < 4; ++nq) {
        pf[nq] = *(const bf16x8*)&Ps[w][nq * 16 + c][ks * 32 + qq * 8];
        Osum[nq] = __builtin_amdgcn_mfma_f32_16x16x32_bf16(ones, pf[nq], Osum[nq], 0, 0, 0);
      }
#pragma unroll
      for (int dt = 0; dt < 4; ++dt) {
        const short* vb = &Vs[buf][dt * 16 + c][0];
        bf16x8 vf = *(const bf16x8*)(vb + ((((ks << 2) + qq) ^ (c & 7)) << 3));
#pragma unroll
        for (int nq = 0; nq < 4; ++nq)
          O[nq][dt] = __builtin_amdgcn_mfma_f32_16x16x32_bf16(vf, pf[nq], O[nq][dt], 0, 0, 0);
      }
    }

    __syncthreads();
  }

  // normalize + store: lane holds q = qbase+nq*16+c; Osum[nq][0] = full row sum
#pragma unroll
  for (int nq = 0; nq < 4; ++nq) {
    float inv = 1.0f / fmaxf(Osum[nq][0], 1e-30f);
    int row = qbase + nq * 16 + c;
#pragma unroll
    for (int dt = 0; dt < 4; ++dt) {
      ushort4 u;
      u.x = (unsigned short)f2bf(O[nq][dt][0] * inv);
      u.y = (unsigned short)f2bf(O[nq][dt][1] * inv);
      u.z = (unsigned short)f2bf(O[nq][dt][2] * inv);
      u.w = (unsigned short)f2bf(O[nq][dt][3] * inv);
      *(ushort4*)(AO + ((size_t)(b * NS + row)) * NHID + h * 64 + dt * 16 + qq * 4) = u;
    }
  }
}

// ---------------------------------------------------------------------------
// Kernel 4: output projection, m97-style staged GEMM (unchanged).
// ---------------------------------------------------------------------------
__global__ __launch_bounds__(256, 2) void oproj(
    const short* __restrict__ X, const short* __restrict__ Wo_b,
    const float* __restrict__ bo, float* __restrict__ out)
{
  __shared__ __align__(16) short As[2][64][64];    // 16 KB
  __shared__ __align__(16) short Bs[2][128][64];   // 32 KB
  const int tid = threadIdx.x;
  const int w = tid >> 6, lane = tid & 63;
  const int c = lane & 15, qq = lane >> 4;
  const int rowbase = blockIdx.x * 64;
  const int colbase = blockIdx.y * 128;
  const int mh = w & 1, nh = w >> 1;

  const int srow = lane >> 3;
  const int sunit = (lane & 7) ^ srow;

  auto stage = [&](int kb, int buf) {
#pragma unroll
    for (int i = 0; i < 6; ++i) {
      int t = w * 6 + i;
      if (t < 8) {
        const short* g = X + (size_t)(rowbase + t * 8 + srow) * NHID
                           + kb * 64 + sunit * 8;
        gl_lds16(g, &As[buf][0][0] + t * 512);
      } else {
        int j = t - 8;
        const short* g = Wo_b + (size_t)(colbase + j * 8 + srow) * NHID
                              + kb * 64 + sunit * 8;
        gl_lds16(g, &Bs[buf][0][0] + j * 512);
      }
    }
  };

  f32x4 acc[2][4];
#pragma unroll
  for (int mt = 0; mt < 2; ++mt)
#pragma unroll
    for (int nt = 0; nt < 4; ++nt) { f32x4 z = {0.f, 0.f, 0.f, 0.f}; acc[mt][nt] = z; }

  stage(0, 0);
  __syncthreads();

  for (int kb = 0; kb < NHID / 64; ++kb) {
    const int buf = kb & 1;
    if (kb < NHID / 64 - 1) stage(kb + 1, buf ^ 1);

    bf16x8 af[2][2];
#pragma unroll
    for (int mt = 0; mt < 2; ++mt) {
      const short* ap = &As[buf][mh * 32 + mt * 16 + c][0];
#pragma unroll
      for (int ks = 0; ks < 2; ++ks)
        af[mt][ks] = *(const bf16x8*)(ap + ((((ks << 2) + qq) ^ (c & 7)) << 3));
    }
#pragma unroll
    for (int nt = 0; nt < 4; ++nt) {
      const short* bp = &Bs[buf][nh * 64 + nt * 16 + c][0];
#pragma unroll
      for (int ks = 0; ks < 2; ++ks) {
        bf16x8 bf = *(const bf16x8*)(bp + ((((ks << 2) + qq) ^ (c & 7)) << 3));
#pragma unroll
        for (int mt = 0; mt < 2; ++mt)
          acc[mt][nt] = __builtin_amdgcn_mfma_f32_16x16x32_bf16(af[mt][ks], bf, acc[mt][nt], 0, 0, 0);
      }
    }

    __syncthreads();
  }

#pragma unroll
  for (int nt = 0; nt < 4; ++nt) {
    int col = colbase + nh * 64 + nt * 16 + c;
    float bias = bo[col];
#pragma unroll
    for (int mt = 0; mt < 2; ++mt) {
      int row = rowbase + mh * 32 + mt * 16 + qq * 4;
#pragma unroll
      for (int r = 0; r < 4; ++r)
        out[(size_t)(row + r) * NHID + col] = acc[mt][nt][r] + bias;
    }
  }
}

// ---------------------------------------------------------------------------
extern "C" void kernel_launch(void* const* d_in, const int* in_sizes, int n_in,
                              void* d_out, int out_size, void* d_ws, size_t ws_size,
                              hipStream_t stream) {
  const float* qin = (const float*)d_in[0];
  const float* kin = (const float*)d_in[1];
  const float* vin = (const float*)d_in[2];
  const int*  mask = (const int*)d_in[3];
  const float* Wq = (const float*)d_in[4];
  const float* bq = (const float*)d_in[5];
  const float* Wk = (const float*)d_in[6];
  const float* bk = (const float*)d_in[7];
  const float* Wv = (const float*)d_in[8];
  const float* bv = (const float*)d_in[9];
  const float* Wo = (const float*)d_in[10];
  const float* bo = (const float*)d_in[11];
  float* out = (float*)d_out;

  char* ws = (char*)d_ws;
  short* Qws = (short*)(ws);                           // 8 MB  [BH,S,64]
  short* Kws = (short*)(ws + (size_t)(8 << 20));       // 8 MB  [BH,S,64]
  short* Vt  = (short*)(ws + (size_t)(16 << 20));      // 8 MB  [BH,64,S]
  short* AO  = (short*)(ws + (size_t)(24 << 20));      // 8 MB  [B,S,HID]
  unsigned* Mp = (unsigned*)(ws + (size_t)(32 << 20)); // 1 MB packed mask
  short* Wo_b = (short*)(ws + (size_t)(33 << 20));     // 2 MB
  short* Wq_b = (short*)(ws + (size_t)(35 << 20));     // 8 KB
  short* Wk_b = (short*)(ws + (size_t)(35 << 20) + 8192);
  short* Wv_b = (short*)(ws + (size_t)(35 << 20) + 16384);

  prep<<<2060, 256, 0, stream>>>(mask, Mp, Wq, Wk, Wv, Wo, Wq_b, Wk_b, Wv_b, Wo_b);
  qk_proj<<<NB * NS / 4, 256, 0, stream>>>(qin, kin, Wq_b, bq, Wk_b, bk, Qws, Kws);
  vproj<<<(NB * NH) * (NS / 64), 256, 0, stream>>>(vin, Wv_b, bv, Vt);
  attn<<<(NB * NH) * (NS / 128), 128, 0, stream>>>(Qws, Kws, Vt, Mp, AO);
  oproj<<<dim3(64, 8), 256, 0, stream>>>(AO, Wo_b, bo, out);
}

// Round 9
// 222.538 us; speedup vs baseline: 1.1038x; 1.1038x over previous
//
#include <hip/hip_runtime.h>
#include <hip/hip_bf16.h>

#define NB 2
#define NS 2048
#define NH 16
#define ND 64
#define NHID 1024

// exp(x/32) = exp2(x * log2(e)/32) ; folded into Wq/bq at conversion time
#define QSCALE 0.045084220f

typedef __attribute__((ext_vector_type(8))) short bf16x8;
typedef __attribute__((ext_vector_type(4))) short s16x4;
typedef __attribute__((ext_vector_type(4))) float f32x4;

typedef __attribute__((address_space(3))) unsigned int lds_u32;
typedef __attribute__((address_space(1))) unsigned int glb_u32;

__device__ inline void gl_lds16(const void* g, void* l) {
  __builtin_amdgcn_global_load_lds((const glb_u32*)g, (lds_u32*)l, 16, 0, 0);
}

__device__ inline short f2bf(float f) {
  __hip_bfloat16 h = __float2bfloat16(f);
  short s; __builtin_memcpy(&s, &h, 2); return s;
}

// packed f32 pair -> bf16x2 dword (v_cvt_pk_bf16_f32 on gfx950)
__device__ inline unsigned pk2bf(float a, float b) {
  float2 t; t.x = a; t.y = b;
  __hip_bfloat162 h = __float22bfloat162_rn(t);
  unsigned u; __builtin_memcpy(&u, &h, 4); return u;
}

__device__ inline bf16x8 cvt8(const float* __restrict__ p) {
  float4 x = *(const float4*)p;
  float4 y = *(const float4*)(p + 4);
  bf16x8 r;
  r[0] = f2bf(x.x); r[1] = f2bf(x.y); r[2] = f2bf(x.z); r[3] = f2bf(x.w);
  r[4] = f2bf(y.x); r[5] = f2bf(y.y); r[6] = f2bf(y.z); r[7] = f2bf(y.w);
  return r;
}

// ---------------------------------------------------------------------------
// Kernel 0: prep = pack_mask (blocks 0..1023) + weight cvt (blocks 1024..2059)
// ---------------------------------------------------------------------------
__global__ __launch_bounds__(256) void prep(
    const int* __restrict__ mask, unsigned* __restrict__ mp,
    const float* __restrict__ Wq, const float* __restrict__ Wk,
    const float* __restrict__ Wv, const float* __restrict__ Wo,
    short* __restrict__ Wq_b, short* __restrict__ Wk_b,
    short* __restrict__ Wv_b, short* __restrict__ Wo_b)
{
  if (blockIdx.x < 1024) {
    int idx = blockIdx.x * 256 + threadIdx.x;          // 0..262143
    const int4* src = (const int4*)(mask + (long)idx * 32);
    unsigned w = 0;
#pragma unroll
    for (int i = 0; i < 8; ++i) {
      int4 v = src[i];
      w |= (v.x != 0 ? 1u : 0u) << (i * 4 + 0);
      w |= (v.y != 0 ? 1u : 0u) << (i * 4 + 1);
      w |= (v.z != 0 ? 1u : 0u) << (i * 4 + 2);
      w |= (v.w != 0 ? 1u : 0u) << (i * 4 + 3);
    }
    mp[idx] = w;
  } else {
    int i = ((blockIdx.x - 1024) * 256 + threadIdx.x) * 4;  // 0..1060860
    const float* src; short* dst; int off; float sc = 1.0f;
    if (i < 1048576)      { src = Wo; dst = Wo_b; off = i; }
    else {
      int j = i - 1048576;
      if (j < 4096)       { src = Wq; dst = Wq_b; off = j; sc = QSCALE; }
      else if (j < 8192)  { src = Wk; dst = Wk_b; off = j - 4096; }
      else                { src = Wv; dst = Wv_b; off = j - 8192; }
    }
    float4 v = *(const float4*)(src + off);
    s16x4 o;
    o[0] = f2bf(v.x * sc); o[1] = f2bf(v.y * sc);
    o[2] = f2bf(v.z * sc); o[3] = f2bf(v.w * sc);
    *(s16x4*)(dst + off) = o;
  }
}

// ---------------------------------------------------------------------------
// Kernel 1: merged QKV projection.
// Blocks 0..1023  : Q,K projection (4 waves, wave = 1 token, 16 heads)
// Blocks 1024..2047: V projection + 64x64 transpose (4 waves, wave = 16 tok)
// ---------------------------------------------------------------------------
__global__ __launch_bounds__(256) void qkv_proj(
    const float* __restrict__ qin, const float* __restrict__ kin,
    const float* __restrict__ vin,
    const short* __restrict__ Wq_b, const float* __restrict__ bq,
    const short* __restrict__ Wk_b, const float* __restrict__ bk,
    const short* __restrict__ Wv_b, const float* __restrict__ bv,
    short* __restrict__ Qws, short* __restrict__ Kws, short* __restrict__ Vt)
{
  __shared__ __align__(16) short ldsT[4][16][72];   // qk path
  __shared__ __align__(16) short ldsVT[64][72];     // v path
  const int tid = threadIdx.x;
  const int w = tid >> 6, lane = tid & 63;
  const int c = lane & 15, qq = lane >> 4;

  if (blockIdx.x < 1024) {
    // ---- Q,K projection ----
    const int t = blockIdx.x * 4 + w;         // b*S + s
    const int b = t >> 11, s = t & (NS - 1);
    const int aoff = (t * 16 + c) * 64 + qq * 8;
    const int row0 = lane >> 3, inner = lane & 7;

#pragma unroll
    for (int m = 0; m < 2; ++m) {
      const float* X  = (m == 0) ? qin  : kin;
      const short* W  = (m == 0) ? Wq_b : Wk_b;
      const float* bb = (m == 0) ? bq   : bk;
      short* dst      = (m == 0) ? Qws  : Kws;
      const float bsc = (m == 0) ? QSCALE : 1.0f;

      bf16x8 a0 = cvt8(X + aoff);
      bf16x8 a1 = cvt8(X + aoff + 32);

#pragma unroll
      for (int nt = 0; nt < 4; ++nt) {
        f32x4 z = {0.f, 0.f, 0.f, 0.f};
        const short* wp = W + (nt * 16 + c) * 64 + qq * 8;
        bf16x8 b0 = *(const bf16x8*)(wp);
        bf16x8 b1 = *(const bf16x8*)(wp + 32);
        z = __builtin_amdgcn_mfma_f32_16x16x32_bf16(a0, b0, z, 0, 0, 0);
        z = __builtin_amdgcn_mfma_f32_16x16x32_bf16(a1, b1, z, 0, 0, 0);
        float bias = bb[nt * 16 + c] * bsc;
#pragma unroll
        for (int r = 0; r < 4; ++r)           // C row = head = qq*4+r
          ldsT[w][qq * 4 + r][nt * 16 + c] = f2bf(z[r] + bias);
      }

      bf16x8 v0 = *(const bf16x8*)&ldsT[w][row0][inner * 8];
      bf16x8 v1 = *(const bf16x8*)&ldsT[w][row0 + 8][inner * 8];
      int bh0 = b * NH + row0, bh1 = b * NH + row0 + 8;
      *(bf16x8*)(dst + (bh0 * NS + s) * 64 + inner * 8) = v0;
      *(bf16x8*)(dst + (bh1 * NS + s) * 64 + inner * 8) = v1;
    }
  } else {
    // ---- V projection + transpose ----
    const int bid = blockIdx.x - 1024;
    const int g = w;
    const int bh = bid >> 5;
    const int stile = bid & 31;
    const int b = bh >> 4, h = bh & 15;
    const int sb = stile * 64;

    bf16x8 wv[8];
    float bias[4];
#pragma unroll
    for (int nt = 0; nt < 4; ++nt) {
      const short* wp = Wv_b + (nt * 16 + c) * 64 + qq * 8;
      wv[nt * 2]     = *(const bf16x8*)(wp);
      wv[nt * 2 + 1] = *(const bf16x8*)(wp + 32);
      bias[nt] = bv[nt * 16 + c];
    }

    const float* ap = vin + ((size_t)((b * NS + sb + 16 * g + c) * 16 + h)) * 64 + qq * 8;
    bf16x8 a0 = cvt8(ap);
    bf16x8 a1 = cvt8(ap + 32);
#pragma unroll
    for (int nt = 0; nt < 4; ++nt) {
      f32x4 z = {0.f, 0.f, 0.f, 0.f};
      z = __builtin_amdgcn_mfma_f32_16x16x32_bf16(a0, wv[nt * 2], z, 0, 0, 0);
      z = __builtin_amdgcn_mfma_f32_16x16x32_bf16(a1, wv[nt * 2 + 1], z, 0, 0, 0);
      uint2 u;
      u.x = pk2bf(z[0] + bias[nt], z[1] + bias[nt]);
      u.y = pk2bf(z[2] + bias[nt], z[3] + bias[nt]);
      *(uint2*)&ldsVT[nt * 16 + c][16 * g + qq * 4] = u;   // token = 16g+qq*4+r
    }
    __syncthreads();

#pragma unroll
    for (int j = 0; j < 2; ++j) {
      int idx = tid + 256 * j;            // 0..511
      int d = idx >> 3, unit = idx & 7;
      bf16x8 o = *(const bf16x8*)&ldsVT[d][unit * 8];
      *(bf16x8*)(Vt + ((size_t)(bh * 64 + d)) * NS + sb + unit * 8) = o;
    }
  }
}

// ---------------------------------------------------------------------------
// Kernel 3: flash attention — round-7 structure (4 waves x nq=2, grid 512)
// + packed bf16 converts (v_cvt_pk_bf16_f32) + row sums via ones-MFMA.
// Mask applied pre-exp: z -> -128 (exp2(-128) ~= 0, consistent in sum).
// ---------------------------------------------------------------------------
__global__ __launch_bounds__(256) void attn(
    const short* __restrict__ Qws, const short* __restrict__ Kws,
    const short* __restrict__ Vt, const unsigned* __restrict__ Mp,
    short* __restrict__ AO)
{
  __shared__ __align__(16) short Ks[2][64][64];   // staged K tile (swizzled)
  __shared__ __align__(16) short Vs[2][64][64];   // staged V tile (swizzled)
  __shared__ __align__(16) short Ps[4][32][72];   // per-wave P^T tile [q][key]

  const int tid = threadIdx.x;
  const int w = tid >> 6, lane = tid & 63;
  const int c = lane & 15, qq = lane >> 4;
  const int bh = blockIdx.x & 31;                 // XCD swizzle
  const int qtile = blockIdx.x >> 5;              // 0..15
  const int b = bh >> 4, h = bh & 15;
  const int qbase = qtile * 128 + w * 32;         // this wave's 32 q-rows

  const short* Qp = Qws + (size_t)bh * (NS * 64);
  const short* Kp = Kws + (size_t)bh * (NS * 64);
  const short* Vp = Vt + (size_t)bh * (64 * NS);
  const unsigned* mrow = Mp + (size_t)b * (NS * (NS / 32));

  // Q B-frags: 2 q-tiles x 2 k-halves (pre-scaled by QSCALE in qkv_proj)
  bf16x8 aq[2][2];
#pragma unroll
  for (int nq = 0; nq < 2; ++nq) {
    const short* qp = Qp + (qbase + nq * 16 + c) * 64 + qq * 8;
    aq[nq][0] = *(const bf16x8*)(qp);
    aq[nq][1] = *(const bf16x8*)(qp + 32);
  }

  // ones A-frag for row-sum MFMA (verified in r8)
  bf16x8 ones;
#pragma unroll
  for (int i = 0; i < 8; ++i) ones[i] = (short)0x3F80;

  const f32x4 ZV = {0.f, 0.f, 0.f, 0.f};
  f32x4 O[2][4];                                  // O^T: [nq][dt], reg = d
  f32x4 Osum[2];                                  // row sums via ones-MFMA
#pragma unroll
  for (int nq = 0; nq < 2; ++nq) {
    Osum[nq] = ZV;
#pragma unroll
    for (int dt = 0; dt < 4; ++dt) O[nq][dt] = ZV;
  }

  const int srow = lane >> 3;
  const int sunit = (lane & 7) ^ srow;            // XOR swizzle (global side)
  auto stage = [&](int kt, int buf) {
#pragma unroll
    for (int i = 0; i < 2; ++i) {
      int j = w * 2 + i;
      const short* gk = Kp + ((size_t)(kt * 64 + j * 8 + srow)) * 64 + sunit * 8;
      gl_lds16(gk, &Ks[buf][0][0] + j * 512);
      const short* gv = Vp + ((size_t)(j * 8 + srow)) * NS + kt * 64 + sunit * 8;
      gl_lds16(gv, &Vs[buf][0][0] + j * 512);
    }
  };

  stage(0, 0);
  __syncthreads();

  for (int kt = 0; kt < NS / 64; ++kt) {
    const int buf = kt & 1;
    if (kt < NS / 64 - 1) stage(kt + 1, buf ^ 1);

    // mask: one 64-bit word per q-row (lane c owns its q)
    uint2 mw[2];
#pragma unroll
    for (int nq = 0; nq < 2; ++nq)
      mw[nq] = *(const uint2*)(mrow +
          (size_t)(qbase + nq * 16 + c) * (NS / 32) + kt * 2);

    // S^T = K.Q^T per 16-key group; mask -> -128 pre-exp; exp2; pk-pack
#pragma unroll
    for (int mt = 0; mt < 4; ++mt) {
      const short* kb = &Ks[buf][mt * 16 + c][0];
      bf16x8 ak0 = *(const bf16x8*)(kb + ((qq ^ (c & 7)) << 3));
      bf16x8 ak1 = *(const bf16x8*)(kb + (((4 + qq) ^ (c & 7)) << 3));
#pragma unroll
      for (int nq = 0; nq < 2; ++nq) {
        f32x4 z = __builtin_amdgcn_mfma_f32_16x16x32_bf16(ak0, aq[nq][0], ZV, 0, 0, 0);
        z = __builtin_amdgcn_mfma_f32_16x16x32_bf16(ak1, aq[nq][1], z, 0, 0, 0);
        unsigned wsel = (mt & 2) ? mw[nq].y : mw[nq].x;
        unsigned nib = (wsel >> (((mt & 1) << 4) + (qq << 2))) & 0xFu;
        float e0 = __builtin_amdgcn_exp2f((nib & 1u) ? z[0] : -128.f);
        float e1 = __builtin_amdgcn_exp2f((nib & 2u) ? z[1] : -128.f);
        float e2 = __builtin_amdgcn_exp2f((nib & 4u) ? z[2] : -128.f);
        float e3 = __builtin_amdgcn_exp2f((nib & 8u) ? z[3] : -128.f);
        uint2 u;
        u.x = pk2bf(e0, e1);
        u.y = pk2bf(e2, e3);
        *(uint2*)&Ps[w][nq * 16 + c][mt * 16 + (qq << 2)] = u;
      }
    }

    // O^T += V^T . P ; row sums via ones-MFMA on the same B-frags
#pragma unroll
    for (int ks = 0; ks < 2; ++ks) {
      bf16x8 pf[2];
#pragma unroll
      for (int nq = 0; nq < 2; ++nq) {
        pf[nq] = *(const bf16x8*)&Ps[w][nq * 16 + c][ks * 32 + qq * 8];
        Osum[nq] = __builtin_amdgcn_mfma_f32_16x16x32_bf16(ones, pf[nq], Osum[nq], 0, 0, 0);
      }
#pragma unroll
      for (int dt = 0; dt < 4; ++dt) {
        const short* vb = &Vs[buf][dt * 16 + c][0];
        bf16x8 vf = *(const bf16x8*)(vb + ((((ks << 2) + qq) ^ (c & 7)) << 3));
#pragma unroll
        for (int nq = 0; nq < 2; ++nq)
          O[nq][dt] = __builtin_amdgcn_mfma_f32_16x16x32_bf16(vf, pf[nq], O[nq][dt], 0, 0, 0);
      }
    }

    __syncthreads();
  }

  // normalize + store: lane holds q = qbase+nq*16+c; Osum[nq][0] = row sum
#pragma unroll
  for (int nq = 0; nq < 2; ++nq) {
    float inv = 1.0f / fmaxf(Osum[nq][0], 1e-30f);
    int row = qbase + nq * 16 + c;
#pragma unroll
    for (int dt = 0; dt < 4; ++dt) {
      uint2 u;
      u.x = pk2bf(O[nq][dt][0] * inv, O[nq][dt][1] * inv);
      u.y = pk2bf(O[nq][dt][2] * inv, O[nq][dt][3] * inv);
      *(uint2*)(AO + ((size_t)(b * NS + row)) * NHID + h * 64 + dt * 16 + qq * 4) = u;
    }
  }
}

// ---------------------------------------------------------------------------
// Kernel 4: output projection, m97-style staged GEMM (unchanged from r7).
// ---------------------------------------------------------------------------
__global__ __launch_bounds__(256, 2) void oproj(
    const short* __restrict__ X, const short* __restrict__ Wo_b,
    const float* __restrict__ bo, float* __restrict__ out)
{
  __shared__ __align__(16) short As[2][64][64];    // 16 KB
  __shared__ __align__(16) short Bs[2][128][64];   // 32 KB
  const int tid = threadIdx.x;
  const int w = tid >> 6, lane = tid & 63;
  const int c = lane & 15, qq = lane >> 4;
  const int rowbase = blockIdx.x * 64;
  const int colbase = blockIdx.y * 128;
  const int mh = w & 1, nh = w >> 1;

  const int srow = lane >> 3;
  const int sunit = (lane & 7) ^ srow;

  auto stage = [&](int kb, int buf) {
#pragma unroll
    for (int i = 0; i < 6; ++i) {
      int t = w * 6 + i;
      if (t < 8) {
        const short* g = X + (size_t)(rowbase + t * 8 + srow) * NHID
                           + kb * 64 + sunit * 8;
        gl_lds16(g, &As[buf][0][0] + t * 512);
      } else {
        int j = t - 8;
        const short* g = Wo_b + (size_t)(colbase + j * 8 + srow) * NHID
                              + kb * 64 + sunit * 8;
        gl_lds16(g, &Bs[buf][0][0] + j * 512);
      }
    }
  };

  f32x4 acc[2][4];
#pragma unroll
  for (int mt = 0; mt < 2; ++mt)
#pragma unroll
    for (int nt = 0; nt < 4; ++nt) { f32x4 z = {0.f, 0.f, 0.f, 0.f}; acc[mt][nt] = z; }

  stage(0, 0);
  __syncthreads();

  for (int kb = 0; kb < NHID / 64; ++kb) {
    const int buf = kb & 1;
    if (kb < NHID / 64 - 1) stage(kb + 1, buf ^ 1);

    bf16x8 af[2][2];
#pragma unroll
    for (int mt = 0; mt < 2; ++mt) {
      const short* ap = &As[buf][mh * 32 + mt * 16 + c][0];
#pragma unroll
      for (int ks = 0; ks < 2; ++ks)
        af[mt][ks] = *(const bf16x8*)(ap + ((((ks << 2) + qq) ^ (c & 7)) << 3));
    }
#pragma unroll
    for (int nt = 0; nt < 4; ++nt) {
      const short* bp = &Bs[buf][nh * 64 + nt * 16 + c][0];
#pragma unroll
      for (int ks = 0; ks < 2; ++ks) {
        bf16x8 bf = *(const bf16x8*)(bp + ((((ks << 2) + qq) ^ (c & 7)) << 3));
#pragma unroll
        for (int mt = 0; mt < 2; ++mt)
          acc[mt][nt] = __builtin_amdgcn_mfma_f32_16x16x32_bf16(af[mt][ks], bf, acc[mt][nt], 0, 0, 0);
      }
    }

    __syncthreads();
  }

#pragma unroll
  for (int nt = 0; nt < 4; ++nt) {
    int col = colbase + nh * 64 + nt * 16 + c;
    float bias = bo[col];
#pragma unroll
    for (int mt = 0; mt < 2; ++mt) {
      int row = rowbase + mh * 32 + mt * 16 + qq * 4;
#pragma unroll
      for (int r = 0; r < 4; ++r)
        out[(size_t)(row + r) * NHID + col] = acc[mt][nt][r] + bias;
    }
  }
}

// ---------------------------------------------------------------------------
extern "C" void kernel_launch(void* const* d_in, const int* in_sizes, int n_in,
                              void* d_out, int out_size, void* d_ws, size_t ws_size,
                              hipStream_t stream) {
  const float* qin = (const float*)d_in[0];
  const float* kin = (const float*)d_in[1];
  const float* vin = (const float*)d_in[2];
  const int*  mask = (const int*)d_in[3];
  const float* Wq = (const float*)d_in[4];
  const float* bq = (const float*)d_in[5];
  const float* Wk = (const float*)d_in[6];
  const float* bk = (const float*)d_in[7];
  const float* Wv = (const float*)d_in[8];
  const float* bv = (const float*)d_in[9];
  const float* Wo = (const float*)d_in[10];
  const float* bo = (const float*)d_in[11];
  float* out = (float*)d_out;

  char* ws = (char*)d_ws;
  short* Qws = (short*)(ws);                           // 8 MB  [BH,S,64]
  short* Kws = (short*)(ws + (size_t)(8 << 20));       // 8 MB  [BH,S,64]
  short* Vt  = (short*)(ws + (size_t)(16 << 20));      // 8 MB  [BH,64,S]
  short* AO  = (short*)(ws + (size_t)(24 << 20));      // 8 MB  [B,S,HID]
  unsigned* Mp = (unsigned*)(ws + (size_t)(32 << 20)); // 1 MB packed mask
  short* Wo_b = (short*)(ws + (size_t)(33 << 20));     // 2 MB
  short* Wq_b = (short*)(ws + (size_t)(35 << 20));     // 8 KB
  short* Wk_b = (short*)(ws + (size_t)(35 << 20) + 8192);
  short* Wv_b = (short*)(ws + (size_t)(35 << 20) + 16384);

  prep<<<2060, 256, 0, stream>>>(mask, Mp, Wq, Wk, Wv, Wo, Wq_b, Wk_b, Wv_b, Wo_b);
  qkv_proj<<<2048, 256, 0, stream>>>(qin, kin, vin, Wq_b, bq, Wk_b, bk, Wv_b, bv,
                                     Qws, Kws, Vt);
  attn<<<(NB * NH) * (NS / 128), 256, 0, stream>>>(Qws, Kws, Vt, Mp, AO);
  oproj<<<dim3(64, 8), 256, 0, stream>>>(AO, Wo_b, bo, out);
}